// Round 1
// baseline (779.084 us; speedup 1.0000x reference)
//
#include <hip/hip_runtime.h>
#include <math.h>

#define N_TOK 1024
#define C_DIM 384
#define H_NUM 12
#define DK_DIM 16
#define DV_DIM 16
#define P_PTS 4
#define HD (H_NUM * DK_DIM)      // 192
#define HP3 (H_NUM * P_PTS * 3)  // 144
#define ATT_W (HD + H_NUM * P_PTS)  // 240
#define COEF 0.11785113019775792f   // 0.5 * sqrt(2/36)
#define INV_SQRT_DK 0.25f

// ---------------- Kernel 1: fused projections x @ [Wq Wk Wv Wqp Wkp Wvp] ----------------
__global__ __launch_bounds__(256) void k_proj(
    const float* __restrict__ x,
    const float* __restrict__ Wq, const float* __restrict__ Wk, const float* __restrict__ Wv,
    const float* __restrict__ Wqp, const float* __restrict__ Wkp, const float* __restrict__ Wvp,
    float* __restrict__ qs, float* __restrict__ ks, float* __restrict__ vs,
    float* __restrict__ qpl, float* __restrict__ kpl, float* __restrict__ vpl)
{
    const int ROWS = 8;
    __shared__ float xr[ROWS][C_DIM];
    int n0 = blockIdx.x * ROWS;
    for (int idx = threadIdx.x; idx < ROWS * C_DIM; idx += 256) {
        int r = idx / C_DIM, c = idx % C_DIM;
        xr[r][c] = x[(n0 + r) * C_DIM + c];
    }
    __syncthreads();

    for (int o = threadIdx.x; o < 1008; o += 256) {
        const float* W; float* dst; int col, od;
        if (o < 576) {
            od = 192; int which = o / 192; col = o % 192;
            W = (which == 0) ? Wq : (which == 1) ? Wk : Wv;
            dst = (which == 0) ? qs : (which == 1) ? ks : vs;
        } else {
            od = 144; int which = (o - 576) / 144; col = (o - 576) % 144;
            W = (which == 0) ? Wqp : (which == 1) ? Wkp : Wvp;
            dst = (which == 0) ? qpl : (which == 1) ? kpl : vpl;
        }
        float acc[ROWS];
#pragma unroll
        for (int r = 0; r < ROWS; ++r) acc[r] = 0.f;
        for (int c = 0; c < C_DIM; ++c) {
            float w = W[c * od + col];
#pragma unroll
            for (int r = 0; r < ROWS; ++r) acc[r] += xr[r][c] * w;
        }
#pragma unroll
        for (int r = 0; r < ROWS; ++r) dst[(n0 + r) * od + col] = acc[r];
    }
}

// ---------------- Kernel 2: apply rotation + translation to point projections ----------------
__global__ __launch_bounds__(256) void k_rot(
    const float* __restrict__ rot, const float* __restrict__ trans,
    const float* __restrict__ qpl, const float* __restrict__ kpl, const float* __restrict__ vpl,
    float* __restrict__ qpg, float* __restrict__ kpg, float* __restrict__ vpg)
{
    int idx = blockIdx.x * 256 + threadIdx.x;   // over 3 * N * 48 point tasks
    if (idx >= 3 * N_TOK * 48) return;
    int type = idx / (N_TOK * 48);
    int rem = idx % (N_TOK * 48);
    int n = rem / 48;
    int pt = rem % 48;
    const float* src = (type == 0) ? qpl : (type == 1) ? kpl : vpl;
    float* dst = (type == 0) ? qpg : (type == 1) ? kpg : vpg;
    float p0 = src[n * HP3 + pt * 3 + 0];
    float p1 = src[n * HP3 + pt * 3 + 1];
    float p2 = src[n * HP3 + pt * 3 + 2];
    const float* R = rot + n * 9;
    const float* t = trans + n * 3;
#pragma unroll
    for (int i = 0; i < 3; ++i) {
        float g = R[i * 3 + 0] * p0 + R[i * 3 + 1] * p1 + R[i * 3 + 2] * p2 + t[i];
        dst[n * HP3 + pt * 3 + i] = g;
    }
}

// ---------------- Kernel 3: per-(n,h) squared norms of global q/k points ----------------
__global__ __launch_bounds__(256) void k_sq(
    const float* __restrict__ qpg, const float* __restrict__ kpg,
    float* __restrict__ q2, float* __restrict__ k2)
{
    int idx = blockIdx.x * 256 + threadIdx.x;  // over 2*N*H
    if (idx >= 2 * N_TOK * H_NUM) return;
    int type = idx / (N_TOK * H_NUM);
    int rem = idx % (N_TOK * H_NUM);
    int n = rem / H_NUM, h = rem % H_NUM;
    const float* src = type ? kpg : qpg;
    float s = 0.f;
#pragma unroll
    for (int pc = 0; pc < 12; ++pc) {
        float v = src[n * HP3 + h * 12 + pc];
        s += v * v;
    }
    (type ? k2 : q2)[n * H_NUM + h] = s;
}

// ---------------- Kernel 4: attention (one wave per (i,h) pair) ----------------
__global__ __launch_bounds__(256) void k_attn(
    const float* __restrict__ qs, const float* __restrict__ ks, const float* __restrict__ vs,
    const float* __restrict__ qpg, const float* __restrict__ kpg, const float* __restrict__ vpg,
    const float* __restrict__ q2, const float* __restrict__ k2,
    const float* __restrict__ rot, const float* __restrict__ trans,
    float* __restrict__ att)
{
    int lane = threadIdx.x & 63;
    int wave = threadIdx.x >> 6;
    int pair = blockIdx.x * 4 + wave;   // N*H = 12288 pairs
    int i = pair / H_NUM;
    int h = pair % H_NUM;

    float q[16], qp[12];
#pragma unroll
    for (int d = 0; d < 16; ++d) q[d] = qs[i * HD + h * 16 + d];
#pragma unroll
    for (int c = 0; c < 12; ++c) qp[c] = qpg[i * HP3 + h * 12 + c];
    float q2i = q2[i * H_NUM + h];

    float m = -1e30f, denom = 0.f;
    float accv[16], accp[12];
#pragma unroll
    for (int d = 0; d < 16; ++d) accv[d] = 0.f;
#pragma unroll
    for (int c = 0; c < 12; ++c) accp[c] = 0.f;

    for (int jb = 0; jb < N_TOK; jb += 64) {
        int j = jb + lane;
        const float* kr = ks + j * HD + h * 16;
        float s = 0.f;
#pragma unroll
        for (int d = 0; d < 16; ++d) s += q[d] * kr[d];
        const float* kpr = kpg + j * HP3 + h * 12;
        float pq = 0.f;
#pragma unroll
        for (int c = 0; c < 12; ++c) pq += qp[c] * kpr[c];
        float dist = q2i + k2[j * H_NUM + h] - 2.f * pq;
        float logit = (s - COEF * dist) * INV_SQRT_DK;

        float mn = fmaxf(m, logit);
        float sc = __expf(m - mn);
        float p = __expf(logit - mn);
        denom = denom * sc + p;
        m = mn;
        const float* vr = vs + j * HD + h * 16;
#pragma unroll
        for (int d = 0; d < 16; ++d) accv[d] = accv[d] * sc + p * vr[d];
        const float* vpr = vpg + j * HP3 + h * 12;
#pragma unroll
        for (int c = 0; c < 12; ++c) accp[c] = accp[c] * sc + p * vpr[c];
    }

    // cross-lane reduction: global max first
    float mg = m;
#pragma unroll
    for (int off = 32; off; off >>= 1) mg = fmaxf(mg, __shfl_xor(mg, off, 64));
    float sc = __expf(m - mg);
    denom *= sc;
#pragma unroll
    for (int d = 0; d < 16; ++d) accv[d] *= sc;
#pragma unroll
    for (int c = 0; c < 12; ++c) accp[c] *= sc;
#pragma unroll
    for (int off = 32; off; off >>= 1) {
        denom += __shfl_xor(denom, off, 64);
#pragma unroll
        for (int d = 0; d < 16; ++d) accv[d] += __shfl_xor(accv[d], off, 64);
#pragma unroll
        for (int c = 0; c < 12; ++c) accp[c] += __shfl_xor(accp[c], off, 64);
    }

    if (lane == 0) {
        float inv = 1.f / denom;
#pragma unroll
        for (int d = 0; d < 16; ++d) att[i * ATT_W + h * 16 + d] = accv[d] * inv;
        const float* R = rot + i * 9;
        float t0 = trans[i * 3 + 0], t1 = trans[i * 3 + 1], t2 = trans[i * 3 + 2];
#pragma unroll
        for (int p = 0; p < 4; ++p) {
            float c0 = accp[p * 3 + 0] * inv - t0;
            float c1 = accp[p * 3 + 1] * inv - t1;
            float c2 = accp[p * 3 + 2] * inv - t2;
            // local[a] = sum_j R[j][a] * c[j]  (R^T)
            float l0 = R[0] * c0 + R[3] * c1 + R[6] * c2;
            float l1 = R[1] * c0 + R[4] * c1 + R[7] * c2;
            float l2 = R[2] * c0 + R[5] * c1 + R[8] * c2;
            att[i * ATT_W + HD + h * 4 + p] = sqrtf(l0 * l0 + l1 * l1 + l2 * l2);
        }
    }
}

// ---------------- Kernel 5: output GEMM att(1024x240) @ Wout(240x384) + bout ----------------
__global__ __launch_bounds__(256) void k_out(
    const float* __restrict__ att, const float* __restrict__ Wout,
    const float* __restrict__ bout, float* __restrict__ out)
{
    const int ROWS = 8;
    __shared__ float ar[ROWS][ATT_W];
    int n0 = blockIdx.x * ROWS;
    for (int idx = threadIdx.x; idx < ROWS * ATT_W; idx += 256) {
        int r = idx / ATT_W, c = idx % ATT_W;
        ar[r][c] = att[(n0 + r) * ATT_W + c];
    }
    __syncthreads();
    for (int c = threadIdx.x; c < C_DIM; c += 256) {
        float acc[ROWS];
#pragma unroll
        for (int r = 0; r < ROWS; ++r) acc[r] = 0.f;
        for (int k = 0; k < ATT_W; ++k) {
            float w = Wout[k * C_DIM + c];
#pragma unroll
            for (int r = 0; r < ROWS; ++r) acc[r] += ar[r][k] * w;
        }
        float b = bout[c];
#pragma unroll
        for (int r = 0; r < ROWS; ++r) out[(n0 + r) * C_DIM + c] = acc[r] + b;
    }
}

extern "C" void kernel_launch(void* const* d_in, const int* in_sizes, int n_in,
                              void* d_out, int out_size, void* d_ws, size_t ws_size,
                              hipStream_t stream) {
    const float* x     = (const float*)d_in[0];
    const float* rot   = (const float*)d_in[1];
    const float* trans = (const float*)d_in[2];
    const float* Wq    = (const float*)d_in[3];
    const float* Wk    = (const float*)d_in[4];
    const float* Wv    = (const float*)d_in[5];
    const float* Wqp   = (const float*)d_in[6];
    const float* Wkp   = (const float*)d_in[7];
    const float* Wvp   = (const float*)d_in[8];
    const float* Wout  = (const float*)d_in[9];
    const float* bout  = (const float*)d_in[10];
    float* out = (float*)d_out;

    float* ws = (float*)d_ws;
    float* qs  = ws;                   // N*192
    float* ks_ = qs  + N_TOK * HD;     // N*192
    float* vs  = ks_ + N_TOK * HD;     // N*192
    float* qpl = vs  + N_TOK * HD;     // N*144
    float* kpl = qpl + N_TOK * HP3;
    float* vpl = kpl + N_TOK * HP3;
    float* qpg = vpl + N_TOK * HP3;
    float* kpg = qpg + N_TOK * HP3;
    float* vpg = kpg + N_TOK * HP3;
    float* q2  = vpg + N_TOK * HP3;    // N*12
    float* k2  = q2  + N_TOK * H_NUM;
    float* att = k2  + N_TOK * H_NUM;  // N*240

    k_proj<<<N_TOK / 8, 256, 0, stream>>>(x, Wq, Wk, Wv, Wqp, Wkp, Wvp,
                                          qs, ks_, vs, qpl, kpl, vpl);
    k_rot<<<(3 * N_TOK * 48 + 255) / 256, 256, 0, stream>>>(rot, trans, qpl, kpl, vpl,
                                                            qpg, kpg, vpg);
    k_sq<<<(2 * N_TOK * H_NUM + 255) / 256, 256, 0, stream>>>(qpg, kpg, q2, k2);
    k_attn<<<N_TOK * H_NUM / 4, 256, 0, stream>>>(qs, ks_, vs, qpg, kpg, vpg,
                                                  q2, k2, rot, trans, att);
    k_out<<<N_TOK / 8, 256, 0, stream>>>(att, Wout, bout, out);
}

// Round 2
// 213.656 us; speedup vs baseline: 3.6464x; 3.6464x over previous
//
#include <hip/hip_runtime.h>
#include <math.h>

#define N_TOK 1024
#define C_DIM 384
#define H_NUM 12
#define HD 192
#define HP3 144
#define ATT_W 240
#define COEF 0.11785113019775792f   // 0.5 * sqrt(2/36)
#define ISD 0.25f                   // 1/sqrt(16)

// ---------------- Kernel 1: projections as register-tiled GEMM (no LDS) ----------------
// grid (32, 21), block 256.  Block tile 32 rows x 48 cols, thread micro-tile 2x3.
// Col tiles: [0,4)Wq->qs  [4,8)Wk->ks_t  [8,12)Wv->vs_t  [12,15)Wqp->qpl [15,18)Wkp->kpl [18,21)Wvp->vpl
__global__ __launch_bounds__(256) void k_proj(
    const float* __restrict__ x,
    const float* __restrict__ Wq, const float* __restrict__ Wk, const float* __restrict__ Wv,
    const float* __restrict__ Wqp, const float* __restrict__ Wkp, const float* __restrict__ Wvp,
    float* __restrict__ qs, float* __restrict__ ks_t, float* __restrict__ vs_t,
    float* __restrict__ qpl, float* __restrict__ kpl, float* __restrict__ vpl)
{
    int ty = threadIdx.x >> 4, tx = threadIdx.x & 15;
    int n0 = blockIdx.x * 32;
    int by = blockIdx.y;
    const float* W; float* dst; int od, c0, mode;
    if (by < 4)       { W = Wq;  dst = qs;   od = 192; c0 = by * 48;        mode = 0; }
    else if (by < 8)  { W = Wk;  dst = ks_t; od = 192; c0 = (by - 4) * 48;  mode = 1; }
    else if (by < 12) { W = Wv;  dst = vs_t; od = 192; c0 = (by - 8) * 48;  mode = 1; }
    else if (by < 15) { W = Wqp; dst = qpl;  od = 144; c0 = (by - 12) * 48; mode = 2; }
    else if (by < 18) { W = Wkp; dst = kpl;  od = 144; c0 = (by - 15) * 48; mode = 2; }
    else              { W = Wvp; dst = vpl;  od = 144; c0 = (by - 18) * 48; mode = 2; }

    int r0 = n0 + ty * 2;
    int cc0 = c0 + tx * 3;
    float acc[2][3] = {{0.f, 0.f, 0.f}, {0.f, 0.f, 0.f}};
    const float4* xr0 = (const float4*)(x + r0 * C_DIM);
    const float4* xr1 = (const float4*)(x + (r0 + 1) * C_DIM);

    for (int k = 0; k < C_DIM; k += 4) {
        float a0[4], a1[4];
        *(float4*)a0 = xr0[k >> 2];
        *(float4*)a1 = xr1[k >> 2];
        const float* wp = W + k * od + cc0;
#pragma unroll
        for (int u = 0; u < 4; ++u) {
            float w0 = wp[u * od + 0];
            float w1 = wp[u * od + 1];
            float w2 = wp[u * od + 2];
            acc[0][0] += a0[u] * w0; acc[0][1] += a0[u] * w1; acc[0][2] += a0[u] * w2;
            acc[1][0] += a1[u] * w0; acc[1][1] += a1[u] * w1; acc[1][2] += a1[u] * w2;
        }
    }

#pragma unroll
    for (int r = 0; r < 2; ++r) {
#pragma unroll
        for (int c = 0; c < 3; ++c) {
            int row = r0 + r, col = cc0 + c;
            float v = acc[r][c];
            if (mode == 0)      dst[row * HD + col] = v;
            else if (mode == 1) dst[(((col >> 4) << 10) + row) * 16 + (col & 15)] = v;
            else                dst[row * HP3 + col] = v;
        }
    }
}

// ---------------- Kernel 2: rotation + translation + squared norms (fused) ----------------
// one thread per (type, n, h): 3*1024*12 = 36864 threads
__global__ __launch_bounds__(256) void k_rotsq(
    const float* __restrict__ rot, const float* __restrict__ trans,
    const float* __restrict__ qpl, const float* __restrict__ kpl, const float* __restrict__ vpl,
    float* __restrict__ qpg, float* __restrict__ kpg_t, float* __restrict__ vpg_t,
    float* __restrict__ q2, float* __restrict__ k2_t)
{
    int idx = blockIdx.x * 256 + threadIdx.x;
    if (idx >= 3 * N_TOK * H_NUM) return;
    int type = idx / (N_TOK * H_NUM);
    int rem = idx % (N_TOK * H_NUM);
    int n = rem / H_NUM, h = rem % H_NUM;
    const float* src = ((type == 0) ? qpl : (type == 1) ? kpl : vpl) + n * HP3 + h * 12;
    float p[12];
    *(float4*)(p + 0) = ((const float4*)src)[0];
    *(float4*)(p + 4) = ((const float4*)src)[1];
    *(float4*)(p + 8) = ((const float4*)src)[2];
    const float* R = rot + n * 9;
    float R00 = R[0], R01 = R[1], R02 = R[2];
    float R10 = R[3], R11 = R[4], R12 = R[5];
    float R20 = R[6], R21 = R[7], R22 = R[8];
    float t0 = trans[n * 3 + 0], t1 = trans[n * 3 + 1], t2 = trans[n * 3 + 2];
    float g[12];
    float sq = 0.f;
#pragma unroll
    for (int pt = 0; pt < 4; ++pt) {
        float p0 = p[pt * 3 + 0], p1 = p[pt * 3 + 1], p2 = p[pt * 3 + 2];
        float g0 = R00 * p0 + R01 * p1 + R02 * p2 + t0;
        float g1 = R10 * p0 + R11 * p1 + R12 * p2 + t1;
        float g2 = R20 * p0 + R21 * p1 + R22 * p2 + t2;
        g[pt * 3 + 0] = g0; g[pt * 3 + 1] = g1; g[pt * 3 + 2] = g2;
        sq += g0 * g0 + g1 * g1 + g2 * g2;
    }
    float* dst;
    if (type == 0) {
        dst = qpg + n * HP3 + h * 12;
        q2[n * H_NUM + h] = sq;
    } else if (type == 1) {
        dst = kpg_t + (h * N_TOK + n) * 12;
        k2_t[h * N_TOK + n] = sq;
    } else {
        dst = vpg_t + (h * N_TOK + n) * 12;
    }
    ((float4*)dst)[0] = *(float4*)(g + 0);
    ((float4*)dst)[1] = *(float4*)(g + 4);
    ((float4*)dst)[2] = *(float4*)(g + 8);
}

// ---------------- Kernel 3: attention, one wave per (i,h); fixed-shift softmax ----------------
// grid (256, 12), block 256 (4 waves; wave w handles i = bx*4+w, h = by)
__global__ __launch_bounds__(256) void k_attn(
    const float* __restrict__ qs, const float* __restrict__ ks_t, const float* __restrict__ vs_t,
    const float* __restrict__ qpg, const float* __restrict__ kpg_t, const float* __restrict__ vpg_t,
    const float* __restrict__ q2, const float* __restrict__ k2_t,
    const float* __restrict__ rot, const float* __restrict__ trans,
    float* __restrict__ att)
{
    __shared__ float red[4][64][33];
    __shared__ float cent[4][12];
    int lane = threadIdx.x & 63;
    int w = threadIdx.x >> 6;
    int i = blockIdx.x * 4 + w;
    int h = blockIdx.y;

    float q[16], qp[12];
    {
        const float4* qv = (const float4*)(qs + i * HD + h * 16);
        *(float4*)(q + 0) = qv[0]; *(float4*)(q + 4) = qv[1];
        *(float4*)(q + 8) = qv[2]; *(float4*)(q + 12) = qv[3];
        const float4* qpv = (const float4*)(qpg + i * HP3 + h * 12);
        *(float4*)(qp + 0) = qpv[0]; *(float4*)(qp + 4) = qpv[1]; *(float4*)(qp + 8) = qpv[2];
    }
    float q2i = q2[i * H_NUM + h];

    const float4* ksb = (const float4*)(ks_t + h * N_TOK * 16);
    const float4* vsb = (const float4*)(vs_t + h * N_TOK * 16);
    const float4* kpb = (const float4*)(kpg_t + h * N_TOK * 12);
    const float4* vpb = (const float4*)(vpg_t + h * N_TOK * 12);
    const float* k2b = k2_t + h * N_TOK;

    float denom = 0.f;
    float accv[16], accp[12];
#pragma unroll
    for (int d = 0; d < 16; ++d) accv[d] = 0.f;
#pragma unroll
    for (int c = 0; c < 12; ++c) accp[c] = 0.f;

    for (int jb = 0; jb < N_TOK; jb += 64) {
        int j = jb + lane;
        float kk[16], kp[12];
        *(float4*)(kk + 0) = ksb[j * 4 + 0];
        *(float4*)(kk + 4) = ksb[j * 4 + 1];
        *(float4*)(kk + 8) = ksb[j * 4 + 2];
        *(float4*)(kk + 12) = ksb[j * 4 + 3];
        *(float4*)(kp + 0) = kpb[j * 3 + 0];
        *(float4*)(kp + 4) = kpb[j * 3 + 1];
        *(float4*)(kp + 8) = kpb[j * 3 + 2];
        float s = 0.f, pq = 0.f;
#pragma unroll
        for (int d = 0; d < 16; ++d) s += q[d] * kk[d];
#pragma unroll
        for (int c = 0; c < 12; ++c) pq += qp[c] * kp[c];
        float dist = q2i + k2b[j] - 2.f * pq;
        float logit = (s - COEF * dist) * ISD;
        float p = __expf(logit - 4.0f);   // logits <= ~1, so shift 4 is always safe
        denom += p;

        float vv[16], vp[12];
        *(float4*)(vv + 0) = vsb[j * 4 + 0];
        *(float4*)(vv + 4) = vsb[j * 4 + 1];
        *(float4*)(vv + 8) = vsb[j * 4 + 2];
        *(float4*)(vv + 12) = vsb[j * 4 + 3];
        *(float4*)(vp + 0) = vpb[j * 3 + 0];
        *(float4*)(vp + 4) = vpb[j * 3 + 1];
        *(float4*)(vp + 8) = vpb[j * 3 + 2];
#pragma unroll
        for (int d = 0; d < 16; ++d) accv[d] += p * vv[d];
#pragma unroll
        for (int c = 0; c < 12; ++c) accp[c] += p * vp[c];
    }

    // LDS transpose reduction of 29 partial sums across the 64 lanes
#pragma unroll
    for (int d = 0; d < 16; ++d) red[w][lane][d] = accv[d];
#pragma unroll
    for (int c = 0; c < 12; ++c) red[w][lane][16 + c] = accp[c];
    red[w][lane][28] = denom;
    __syncthreads();

    float sum = 0.f;
    if (lane < 29) {
#pragma unroll
        for (int l = 0; l < 64; ++l) sum += red[w][l][lane];
    }
    float den = __shfl(sum, 28, 64);
    float inv = 1.f / den;

    if (lane < 16) att[i * ATT_W + h * 16 + lane] = sum * inv;
    if (lane >= 16 && lane < 28) {
        int s2 = lane - 16;
        cent[w][s2] = sum * inv - trans[i * 3 + s2 % 3];
    }
    __syncthreads();
    if (lane < 4) {
        float c0 = cent[w][lane * 3 + 0];
        float c1 = cent[w][lane * 3 + 1];
        float c2 = cent[w][lane * 3 + 2];
        const float* R = rot + i * 9;
        float l0 = R[0] * c0 + R[3] * c1 + R[6] * c2;
        float l1 = R[1] * c0 + R[4] * c1 + R[7] * c2;
        float l2 = R[2] * c0 + R[5] * c1 + R[8] * c2;
        att[i * ATT_W + HD + h * 4 + lane] = sqrtf(l0 * l0 + l1 * l1 + l2 * l2);
    }
}

// ---------------- Kernel 4: out GEMM att(1024x240) @ Wout(240x384) + bout ----------------
// grid (32, 8), block 256. Block tile 32x48, thread micro 2x3, no LDS.
__global__ __launch_bounds__(256) void k_out(
    const float* __restrict__ att, const float* __restrict__ Wout,
    const float* __restrict__ bout, float* __restrict__ out)
{
    int ty = threadIdx.x >> 4, tx = threadIdx.x & 15;
    int r0 = blockIdx.x * 32 + ty * 2;
    int cc0 = blockIdx.y * 48 + tx * 3;
    float acc[2][3] = {{0.f, 0.f, 0.f}, {0.f, 0.f, 0.f}};
    const float4* ar0 = (const float4*)(att + r0 * ATT_W);
    const float4* ar1 = (const float4*)(att + (r0 + 1) * ATT_W);
    for (int k = 0; k < ATT_W; k += 4) {
        float a0[4], a1[4];
        *(float4*)a0 = ar0[k >> 2];
        *(float4*)a1 = ar1[k >> 2];
        const float* wp = Wout + k * C_DIM + cc0;
#pragma unroll
        for (int u = 0; u < 4; ++u) {
            float w0 = wp[u * C_DIM + 0];
            float w1 = wp[u * C_DIM + 1];
            float w2 = wp[u * C_DIM + 2];
            acc[0][0] += a0[u] * w0; acc[0][1] += a0[u] * w1; acc[0][2] += a0[u] * w2;
            acc[1][0] += a1[u] * w0; acc[1][1] += a1[u] * w1; acc[1][2] += a1[u] * w2;
        }
    }
    float b0 = bout[cc0], b1 = bout[cc0 + 1], b2 = bout[cc0 + 2];
    out[r0 * C_DIM + cc0] = acc[0][0] + b0;
    out[r0 * C_DIM + cc0 + 1] = acc[0][1] + b1;
    out[r0 * C_DIM + cc0 + 2] = acc[0][2] + b2;
    out[(r0 + 1) * C_DIM + cc0] = acc[1][0] + b0;
    out[(r0 + 1) * C_DIM + cc0 + 1] = acc[1][1] + b1;
    out[(r0 + 1) * C_DIM + cc0 + 2] = acc[1][2] + b2;
}

extern "C" void kernel_launch(void* const* d_in, const int* in_sizes, int n_in,
                              void* d_out, int out_size, void* d_ws, size_t ws_size,
                              hipStream_t stream) {
    const float* x     = (const float*)d_in[0];
    const float* rot   = (const float*)d_in[1];
    const float* trans = (const float*)d_in[2];
    const float* Wq    = (const float*)d_in[3];
    const float* Wk    = (const float*)d_in[4];
    const float* Wv    = (const float*)d_in[5];
    const float* Wqp   = (const float*)d_in[6];
    const float* Wkp   = (const float*)d_in[7];
    const float* Wvp   = (const float*)d_in[8];
    const float* Wout  = (const float*)d_in[9];
    const float* bout  = (const float*)d_in[10];
    float* out = (float*)d_out;

    float* ws = (float*)d_ws;
    float* qs    = ws;                      // N*192
    float* ks_t  = qs   + N_TOK * HD;       // [h][j][16]
    float* vs_t  = ks_t + N_TOK * HD;       // [h][j][16]
    float* qpl   = vs_t + N_TOK * HD;       // N*144
    float* kpl   = qpl  + N_TOK * HP3;
    float* vpl   = kpl  + N_TOK * HP3;
    float* qpg   = vpl  + N_TOK * HP3;      // N*144 natural
    float* kpg_t = qpg  + N_TOK * HP3;      // [h][j][12]
    float* vpg_t = kpg_t + N_TOK * HP3;     // [h][j][12]
    float* q2    = vpg_t + N_TOK * HP3;     // N*12
    float* k2_t  = q2   + N_TOK * H_NUM;    // [h][j]
    float* att   = k2_t + N_TOK * H_NUM;    // N*240

    k_proj<<<dim3(32, 21), 256, 0, stream>>>(x, Wq, Wk, Wv, Wqp, Wkp, Wvp,
                                             qs, ks_t, vs_t, qpl, kpl, vpl);
    k_rotsq<<<(3 * N_TOK * H_NUM + 255) / 256, 256, 0, stream>>>(
        rot, trans, qpl, kpl, vpl, qpg, kpg_t, vpg_t, q2, k2_t);
    k_attn<<<dim3(256, 12), 256, 0, stream>>>(qs, ks_t, vs_t, qpg, kpg_t, vpg_t,
                                              q2, k2_t, rot, trans, att);
    k_out<<<dim3(32, 8), 256, 0, stream>>>(att, Wout, bout, out);
}

// Round 4
// 149.419 us; speedup vs baseline: 5.2141x; 1.4299x over previous
//
#include <hip/hip_runtime.h>
#include <math.h>

#define N_TOK 1024
#define C_DIM 384
#define H_NUM 12
#define PCOLS 1024
#define HP3_ROW 144
#define Q0 0
#define K0 192
#define V0 384
#define QP0 576
#define KP0 720
#define VP0 864
#define ATT_W 240
#define COEF 0.11785113019775792f   // 0.5*sqrt(2/36)
#define ISD 0.25f
#define CC2 (COEF * ISD)            // 0.029462...

// ---------- pack 6 weight mats into Wall[384][1024] (cols 1008..1023 zero) ----------
__global__ __launch_bounds__(256) void k_pack(
    const float* __restrict__ Wq, const float* __restrict__ Wk, const float* __restrict__ Wv,
    const float* __restrict__ Wqp, const float* __restrict__ Wkp, const float* __restrict__ Wvp,
    float* __restrict__ Wall)
{
    int t = blockIdx.x * 256 + threadIdx.x;      // 384*256 threads
    int k = t >> 8;
    int col = (t & 255) * 4;
    float4 v;
    if (col < 192)       v = *(const float4*)(Wq  + k * 192 + col);
    else if (col < 384)  v = *(const float4*)(Wk  + k * 192 + col - 192);
    else if (col < 576)  v = *(const float4*)(Wv  + k * 192 + col - 384);
    else if (col < 720)  v = *(const float4*)(Wqp + k * 144 + col - 576);
    else if (col < 864)  v = *(const float4*)(Wkp + k * 144 + col - 720);
    else if (col < 1008) v = *(const float4*)(Wvp + k * 144 + col - 864);
    else                 v = make_float4(0.f, 0.f, 0.f, 0.f);
    *(float4*)(Wall + k * PCOLS + col) = v;
}

// ---------- proj GEMM: P[1024][1024] = x[1024][384] @ Wall[384][1024] ----------
// grid (16,16), 256 thr. BM=BN=64, BK=16, micro 4x4, reg-prefetch double-buffer.
__global__ __launch_bounds__(256) void k_proj(
    const float* __restrict__ x, const float* __restrict__ Wall, float* __restrict__ P)
{
    __shared__ float xs[64][17];
    __shared__ float wsh[16][64];
    int tid = threadIdx.x;
    int i0 = blockIdx.x * 64, c0 = blockIdx.y * 64;
    int lr = tid >> 2, lk = (tid & 3) * 4;
    int wr = tid >> 4, wc = (tid & 15) * 4;
    int ty = tid >> 4, tx = tid & 15;

    float4 xa = *(const float4*)(x + (i0 + lr) * C_DIM + lk);
    float4 wa = *(const float4*)(Wall + wr * PCOLS + c0 + wc);
    float acc[4][4] = {};

    for (int it = 0; it < 24; ++it) {
        xs[lr][lk + 0] = xa.x; xs[lr][lk + 1] = xa.y;
        xs[lr][lk + 2] = xa.z; xs[lr][lk + 3] = xa.w;
        *(float4*)&wsh[wr][wc] = wa;
        __syncthreads();
        if (it < 23) {
            xa = *(const float4*)(x + (i0 + lr) * C_DIM + (it + 1) * 16 + lk);
            wa = *(const float4*)(Wall + ((it + 1) * 16 + wr) * PCOLS + c0 + wc);
        }
#pragma unroll
        for (int kk = 0; kk < 16; ++kk) {
            float4 b = *(float4*)&wsh[kk][tx * 4];
            float a0 = xs[ty * 4 + 0][kk];
            float a1 = xs[ty * 4 + 1][kk];
            float a2 = xs[ty * 4 + 2][kk];
            float a3 = xs[ty * 4 + 3][kk];
            acc[0][0] = fmaf(a0, b.x, acc[0][0]); acc[0][1] = fmaf(a0, b.y, acc[0][1]);
            acc[0][2] = fmaf(a0, b.z, acc[0][2]); acc[0][3] = fmaf(a0, b.w, acc[0][3]);
            acc[1][0] = fmaf(a1, b.x, acc[1][0]); acc[1][1] = fmaf(a1, b.y, acc[1][1]);
            acc[1][2] = fmaf(a1, b.z, acc[1][2]); acc[1][3] = fmaf(a1, b.w, acc[1][3]);
            acc[2][0] = fmaf(a2, b.x, acc[2][0]); acc[2][1] = fmaf(a2, b.y, acc[2][1]);
            acc[2][2] = fmaf(a2, b.z, acc[2][2]); acc[2][3] = fmaf(a2, b.w, acc[2][3]);
            acc[3][0] = fmaf(a3, b.x, acc[3][0]); acc[3][1] = fmaf(a3, b.y, acc[3][1]);
            acc[3][2] = fmaf(a3, b.z, acc[3][2]); acc[3][3] = fmaf(a3, b.w, acc[3][3]);
        }
        __syncthreads();
    }
#pragma unroll
    for (int r = 0; r < 4; ++r) {
        *(float4*)(P + (i0 + ty * 4 + r) * PCOLS + c0 + tx * 4) =
            make_float4(acc[r][0], acc[r][1], acc[r][2], acc[r][3]);
    }
}

// ---------- rot/translate/sq-norm: one thread per (n,h), all 3 point types ----------
__global__ __launch_bounds__(256) void k_rotsq(
    const float* __restrict__ P, const float* __restrict__ rot, const float* __restrict__ trans,
    float* __restrict__ qpg, float* __restrict__ kpg, float* __restrict__ vpg,
    float* __restrict__ q2, float* __restrict__ k2)
{
    int t = blockIdx.x * 256 + threadIdx.x;
    if (t >= N_TOK * H_NUM) return;
    int n = t / H_NUM, h = t % H_NUM;
    const float* R = rot + n * 9;
    float R00 = R[0], R01 = R[1], R02 = R[2];
    float R10 = R[3], R11 = R[4], R12 = R[5];
    float R20 = R[6], R21 = R[7], R22 = R[8];
    float t0 = trans[n * 3 + 0], t1 = trans[n * 3 + 1], t2 = trans[n * 3 + 2];

#pragma unroll
    for (int type = 0; type < 3; ++type) {
        int srcoff = (type == 0) ? QP0 : (type == 1) ? KP0 : VP0;
        const float* src = P + n * PCOLS + srcoff + h * 12;
        float p[12];
        *(float4*)(p + 0) = ((const float4*)src)[0];
        *(float4*)(p + 4) = ((const float4*)src)[1];
        *(float4*)(p + 8) = ((const float4*)src)[2];
        float g[12];
        float sq = 0.f;
#pragma unroll
        for (int pt = 0; pt < 4; ++pt) {
            float p0 = p[pt * 3 + 0], p1 = p[pt * 3 + 1], p2 = p[pt * 3 + 2];
            float g0 = R00 * p0 + R01 * p1 + R02 * p2 + t0;
            float g1 = R10 * p0 + R11 * p1 + R12 * p2 + t1;
            float g2 = R20 * p0 + R21 * p1 + R22 * p2 + t2;
            g[pt * 3 + 0] = g0; g[pt * 3 + 1] = g1; g[pt * 3 + 2] = g2;
            sq += g0 * g0 + g1 * g1 + g2 * g2;
        }
        float* dst = ((type == 0) ? qpg : (type == 1) ? kpg : vpg) + n * HP3_ROW + h * 12;
        ((float4*)dst)[0] = *(float4*)(g + 0);
        ((float4*)dst)[1] = *(float4*)(g + 4);
        ((float4*)dst)[2] = *(float4*)(g + 8);
        if (type == 0) q2[n * H_NUM + h] = sq;
        if (type == 1) k2[n * H_NUM + h] = sq;
    }
}

// ---------- attention: lane = query, wave = j-chunk ----------
// grid (16, 12), 512 thr (8 waves). Block: h = by, queries i0 = bx*64 + lane.
__global__ __launch_bounds__(512) void k_attn(
    const float* __restrict__ P, const float* __restrict__ qpg, const float* __restrict__ kpg,
    const float* __restrict__ vpg, const float* __restrict__ q2, const float* __restrict__ k2,
    const float* __restrict__ rot, const float* __restrict__ trans, float* __restrict__ att)
{
    __shared__ float red[8][29][64];
    int tid = threadIdx.x, lane = tid & 63, w = tid >> 6;
    int h = blockIdx.y;
    int i = blockIdx.x * 64 + lane;

    float q[16], qp[12];
    {
        const float4* qv = (const float4*)(P + i * PCOLS + Q0 + h * 16);
        *(float4*)(q + 0) = qv[0]; *(float4*)(q + 4) = qv[1];
        *(float4*)(q + 8) = qv[2]; *(float4*)(q + 12) = qv[3];
        const float4* qpv = (const float4*)(qpg + i * HP3_ROW + h * 12);
        *(float4*)(qp + 0) = qpv[0]; *(float4*)(qp + 4) = qpv[1]; *(float4*)(qp + 8) = qpv[2];
    }
    float qc = fmaf(-CC2, q2[i * H_NUM + h], -4.0f);   // fold shift + q2 term

    float accv[16] = {}, accp[12] = {};
    float denom = 0.f;

    int j0 = w * 128;
    for (int j = j0; j < j0 + 128; ++j) {
        const float* kr  = P + j * PCOLS + K0 + h * 16;
        const float* vr  = P + j * PCOLS + V0 + h * 16;
        const float* kpr = kpg + j * HP3_ROW + h * 12;
        const float* vpr = vpg + j * HP3_ROW + h * 12;
        float k2j = k2[j * H_NUM + h];

        float s = 0.f, pq = 0.f;
#pragma unroll
        for (int d = 0; d < 16; ++d) s = fmaf(q[d], kr[d], s);
#pragma unroll
        for (int c = 0; c < 12; ++c) pq = fmaf(qp[c], kpr[c], pq);
        float logit = fmaf(ISD, s, fmaf(2.f * CC2, pq, fmaf(-CC2, k2j, qc)));
        float p = __expf(logit);
        denom += p;
#pragma unroll
        for (int d = 0; d < 16; ++d) accv[d] = fmaf(p, vr[d], accv[d]);
#pragma unroll
        for (int c = 0; c < 12; ++c) accp[c] = fmaf(p, vpr[c], accp[c]);
    }

#pragma unroll
    for (int d = 0; d < 16; ++d) red[w][d][lane] = accv[d];
#pragma unroll
    for (int c = 0; c < 12; ++c) red[w][16 + c][lane] = accp[c];
    red[w][28][lane] = denom;
    __syncthreads();

    // sum the 8 wave-partials: 29*64 = 1856 tasks over 512 threads
    for (int t2 = tid; t2 < 29 * 64; t2 += 512) {
        int c = t2 >> 6, qq = t2 & 63;
        float s = red[0][c][qq];
#pragma unroll
        for (int ww = 1; ww < 8; ++ww) s += red[ww][c][qq];
        red[0][c][qq] = s;
    }
    __syncthreads();

    if (tid < 64) {
        float inv = 1.f / red[0][28][lane];
        float* arow = att + i * ATT_W;
#pragma unroll
        for (int d = 0; d < 16; ++d) arow[h * 16 + d] = red[0][d][lane] * inv;
        float t0 = trans[i * 3 + 0], t1 = trans[i * 3 + 1], t2v = trans[i * 3 + 2];
        const float* R = rot + i * 9;
#pragma unroll
        for (int p = 0; p < 4; ++p) {
            float c0 = red[0][16 + p * 3 + 0][lane] * inv - t0;
            float c1 = red[0][16 + p * 3 + 1][lane] * inv - t1;
            float c2 = red[0][16 + p * 3 + 2][lane] * inv - t2v;
            float l0 = R[0] * c0 + R[3] * c1 + R[6] * c2;
            float l1 = R[1] * c0 + R[4] * c1 + R[7] * c2;
            float l2 = R[2] * c0 + R[5] * c1 + R[8] * c2;
            arow[192 + h * 4 + p] = sqrtf(l0 * l0 + l1 * l1 + l2 * l2);
        }
    }
}

// ---------- out GEMM: out[1024][384] = att[1024][240] @ Wout[240][384] + bout ----------
// grid (16,6), 256 thr. BM=BN=64, BK=16, micro 4x4.
__global__ __launch_bounds__(256) void k_out(
    const float* __restrict__ att, const float* __restrict__ Wout,
    const float* __restrict__ bout, float* __restrict__ out)
{
    __shared__ float xs[64][17];
    __shared__ float wsh[16][64];
    int tid = threadIdx.x;
    int i0 = blockIdx.x * 64, c0 = blockIdx.y * 64;
    int lr = tid >> 2, lk = (tid & 3) * 4;
    int wr = tid >> 4, wc = (tid & 15) * 4;
    int ty = tid >> 4, tx = tid & 15;

    float4 xa = *(const float4*)(att + (i0 + lr) * ATT_W + lk);
    float4 wa = *(const float4*)(Wout + wr * C_DIM + c0 + wc);
    float acc[4][4] = {};

    for (int it = 0; it < 15; ++it) {
        xs[lr][lk + 0] = xa.x; xs[lr][lk + 1] = xa.y;
        xs[lr][lk + 2] = xa.z; xs[lr][lk + 3] = xa.w;
        *(float4*)&wsh[wr][wc] = wa;
        __syncthreads();
        if (it < 14) {
            xa = *(const float4*)(att + (i0 + lr) * ATT_W + (it + 1) * 16 + lk);
            wa = *(const float4*)(Wout + ((it + 1) * 16 + wr) * C_DIM + c0 + wc);
        }
#pragma unroll
        for (int kk = 0; kk < 16; ++kk) {
            float4 b = *(float4*)&wsh[kk][tx * 4];
            float a0 = xs[ty * 4 + 0][kk];
            float a1 = xs[ty * 4 + 1][kk];
            float a2 = xs[ty * 4 + 2][kk];
            float a3 = xs[ty * 4 + 3][kk];
            acc[0][0] = fmaf(a0, b.x, acc[0][0]); acc[0][1] = fmaf(a0, b.y, acc[0][1]);
            acc[0][2] = fmaf(a0, b.z, acc[0][2]); acc[0][3] = fmaf(a0, b.w, acc[0][3]);
            acc[1][0] = fmaf(a1, b.x, acc[1][0]); acc[1][1] = fmaf(a1, b.y, acc[1][1]);
            acc[1][2] = fmaf(a1, b.z, acc[1][2]); acc[1][3] = fmaf(a1, b.w, acc[1][3]);
            acc[2][0] = fmaf(a2, b.x, acc[2][0]); acc[2][1] = fmaf(a2, b.y, acc[2][1]);
            acc[2][2] = fmaf(a2, b.z, acc[2][2]); acc[2][3] = fmaf(a2, b.w, acc[2][3]);
            acc[3][0] = fmaf(a3, b.x, acc[3][0]); acc[3][1] = fmaf(a3, b.y, acc[3][1]);
            acc[3][2] = fmaf(a3, b.z, acc[3][2]); acc[3][3] = fmaf(a3, b.w, acc[3][3]);
        }
        __syncthreads();
    }
    float4 bb = *(const float4*)(bout + c0 + tx * 4);
#pragma unroll
    for (int r = 0; r < 4; ++r) {
        *(float4*)(out + (i0 + ty * 4 + r) * C_DIM + c0 + tx * 4) =
            make_float4(acc[r][0] + bb.x, acc[r][1] + bb.y, acc[r][2] + bb.z, acc[r][3] + bb.w);
    }
}

extern "C" void kernel_launch(void* const* d_in, const int* in_sizes, int n_in,
                              void* d_out, int out_size, void* d_ws, size_t ws_size,
                              hipStream_t stream) {
    const float* x     = (const float*)d_in[0];
    const float* rot   = (const float*)d_in[1];
    const float* trans = (const float*)d_in[2];
    const float* Wq    = (const float*)d_in[3];
    const float* Wk    = (const float*)d_in[4];
    const float* Wv    = (const float*)d_in[5];
    const float* Wqp   = (const float*)d_in[6];
    const float* Wkp   = (const float*)d_in[7];
    const float* Wvp   = (const float*)d_in[8];
    const float* Wout  = (const float*)d_in[9];
    const float* bout  = (const float*)d_in[10];
    float* out = (float*)d_out;

    float* ws = (float*)d_ws;
    float* Wall = ws;                         // 384*1024
    float* P    = Wall + C_DIM * PCOLS;       // 1024*1024
    float* qpg  = P    + N_TOK * PCOLS;       // 1024*144
    float* kpg  = qpg  + N_TOK * HP3_ROW;
    float* vpg  = kpg  + N_TOK * HP3_ROW;
    float* q2   = vpg  + N_TOK * HP3_ROW;     // 1024*12
    float* k2   = q2   + N_TOK * H_NUM;
    float* att  = k2   + N_TOK * H_NUM;       // 1024*240

    k_pack<<<384, 256, 0, stream>>>(Wq, Wk, Wv, Wqp, Wkp, Wvp, Wall);
    k_proj<<<dim3(16, 16), 256, 0, stream>>>(x, Wall, P);
    k_rotsq<<<(N_TOK * H_NUM + 255) / 256, 256, 0, stream>>>(P, rot, trans,
                                                             qpg, kpg, vpg, q2, k2);
    k_attn<<<dim3(16, 12), 512, 0, stream>>>(P, qpg, kpg, vpg, q2, k2, rot, trans, att);
    k_out<<<dim3(16, 6), 256, 0, stream>>>(att, Wout, bout, out);
}

// Round 5
// 104.514 us; speedup vs baseline: 7.4543x; 1.4297x over previous
//
#include <hip/hip_runtime.h>
#include <math.h>

#define N_TOK 1024
#define C_DIM 384
#define H_NUM 12
#define PCOLS 1024
#define HP3_ROW 144
#define Q0 0
#define K0 192
#define V0 384
#define QP0 576
#define KP0 720
#define VP0 864
#define ATT_W 240
#define COEF 0.11785113019775792f   // 0.5*sqrt(2/36)
#define ISD 0.25f
#define CC2 (COEF * ISD)            // 0.029462...

// LDS tile layout (floats), tile = 256 keys
#define TJ 256
#define OK_ 0
#define OV_ 4096
#define OKP_ 8192
#define OVP_ 11264
#define OK2_ 14336
#define BUF_F 14592

// ---------- pack 6 weight mats into Wall[384][1024] (cols 1008..1023 zero) ----------
__global__ __launch_bounds__(256) void k_pack(
    const float* __restrict__ Wq, const float* __restrict__ Wk, const float* __restrict__ Wv,
    const float* __restrict__ Wqp, const float* __restrict__ Wkp, const float* __restrict__ Wvp,
    float* __restrict__ Wall)
{
    int t = blockIdx.x * 256 + threadIdx.x;      // 384*256 threads
    int k = t >> 8;
    int col = (t & 255) * 4;
    float4 v;
    if (col < 192)       v = *(const float4*)(Wq  + k * 192 + col);
    else if (col < 384)  v = *(const float4*)(Wk  + k * 192 + col - 192);
    else if (col < 576)  v = *(const float4*)(Wv  + k * 192 + col - 384);
    else if (col < 720)  v = *(const float4*)(Wqp + k * 144 + col - 576);
    else if (col < 864)  v = *(const float4*)(Wkp + k * 144 + col - 720);
    else if (col < 1008) v = *(const float4*)(Wvp + k * 144 + col - 864);
    else                 v = make_float4(0.f, 0.f, 0.f, 0.f);
    *(float4*)(Wall + k * PCOLS + col) = v;
}

// ---------- proj GEMM: P[1024][1024] = x[1024][384] @ Wall[384][1024] ----------
__global__ __launch_bounds__(256) void k_proj(
    const float* __restrict__ x, const float* __restrict__ Wall, float* __restrict__ P)
{
    __shared__ float xs[64][17];
    __shared__ float wsh[16][64];
    int tid = threadIdx.x;
    int i0 = blockIdx.x * 64, c0 = blockIdx.y * 64;
    int lr = tid >> 2, lk = (tid & 3) * 4;
    int wr = tid >> 4, wc = (tid & 15) * 4;
    int ty = tid >> 4, tx = tid & 15;

    float4 xa = *(const float4*)(x + (i0 + lr) * C_DIM + lk);
    float4 wa = *(const float4*)(Wall + wr * PCOLS + c0 + wc);
    float acc[4][4] = {};

    for (int it = 0; it < 24; ++it) {
        xs[lr][lk + 0] = xa.x; xs[lr][lk + 1] = xa.y;
        xs[lr][lk + 2] = xa.z; xs[lr][lk + 3] = xa.w;
        *(float4*)&wsh[wr][wc] = wa;
        __syncthreads();
        if (it < 23) {
            xa = *(const float4*)(x + (i0 + lr) * C_DIM + (it + 1) * 16 + lk);
            wa = *(const float4*)(Wall + ((it + 1) * 16 + wr) * PCOLS + c0 + wc);
        }
#pragma unroll
        for (int kk = 0; kk < 16; ++kk) {
            float4 b = *(float4*)&wsh[kk][tx * 4];
            float a0 = xs[ty * 4 + 0][kk];
            float a1 = xs[ty * 4 + 1][kk];
            float a2 = xs[ty * 4 + 2][kk];
            float a3 = xs[ty * 4 + 3][kk];
            acc[0][0] = fmaf(a0, b.x, acc[0][0]); acc[0][1] = fmaf(a0, b.y, acc[0][1]);
            acc[0][2] = fmaf(a0, b.z, acc[0][2]); acc[0][3] = fmaf(a0, b.w, acc[0][3]);
            acc[1][0] = fmaf(a1, b.x, acc[1][0]); acc[1][1] = fmaf(a1, b.y, acc[1][1]);
            acc[1][2] = fmaf(a1, b.z, acc[1][2]); acc[1][3] = fmaf(a1, b.w, acc[1][3]);
            acc[2][0] = fmaf(a2, b.x, acc[2][0]); acc[2][1] = fmaf(a2, b.y, acc[2][1]);
            acc[2][2] = fmaf(a2, b.z, acc[2][2]); acc[2][3] = fmaf(a2, b.w, acc[2][3]);
            acc[3][0] = fmaf(a3, b.x, acc[3][0]); acc[3][1] = fmaf(a3, b.y, acc[3][1]);
            acc[3][2] = fmaf(a3, b.z, acc[3][2]); acc[3][3] = fmaf(a3, b.w, acc[3][3]);
        }
        __syncthreads();
    }
#pragma unroll
    for (int r = 0; r < 4; ++r) {
        *(float4*)(P + (i0 + ty * 4 + r) * PCOLS + c0 + tx * 4) =
            make_float4(acc[r][0], acc[r][1], acc[r][2], acc[r][3]);
    }
}

// ---------- rot/translate/sq-norm; kp/vp/k2 written head-transposed ----------
__global__ __launch_bounds__(256) void k_rotsq(
    const float* __restrict__ P, const float* __restrict__ rot, const float* __restrict__ trans,
    float* __restrict__ qpg, float* __restrict__ kpg_t, float* __restrict__ vpg_t,
    float* __restrict__ q2, float* __restrict__ k2_t)
{
    int t = blockIdx.x * 256 + threadIdx.x;
    if (t >= N_TOK * H_NUM) return;
    int n = t / H_NUM, h = t % H_NUM;
    const float* R = rot + n * 9;
    float R00 = R[0], R01 = R[1], R02 = R[2];
    float R10 = R[3], R11 = R[4], R12 = R[5];
    float R20 = R[6], R21 = R[7], R22 = R[8];
    float t0 = trans[n * 3 + 0], t1 = trans[n * 3 + 1], t2 = trans[n * 3 + 2];

#pragma unroll
    for (int type = 0; type < 3; ++type) {
        int srcoff = (type == 0) ? QP0 : (type == 1) ? KP0 : VP0;
        const float* src = P + n * PCOLS + srcoff + h * 12;
        float p[12];
        *(float4*)(p + 0) = ((const float4*)src)[0];
        *(float4*)(p + 4) = ((const float4*)src)[1];
        *(float4*)(p + 8) = ((const float4*)src)[2];
        float g[12];
        float sq = 0.f;
#pragma unroll
        for (int pt = 0; pt < 4; ++pt) {
            float p0 = p[pt * 3 + 0], p1 = p[pt * 3 + 1], p2 = p[pt * 3 + 2];
            float g0 = R00 * p0 + R01 * p1 + R02 * p2 + t0;
            float g1 = R10 * p0 + R11 * p1 + R12 * p2 + t1;
            float g2 = R20 * p0 + R21 * p1 + R22 * p2 + t2;
            g[pt * 3 + 0] = g0; g[pt * 3 + 1] = g1; g[pt * 3 + 2] = g2;
            sq += g0 * g0 + g1 * g1 + g2 * g2;
        }
        float* dst;
        if (type == 0)      dst = qpg + n * HP3_ROW + h * 12;
        else if (type == 1) dst = kpg_t + (h * N_TOK + n) * 12;
        else                dst = vpg_t + (h * N_TOK + n) * 12;
        ((float4*)dst)[0] = *(float4*)(g + 0);
        ((float4*)dst)[1] = *(float4*)(g + 4);
        ((float4*)dst)[2] = *(float4*)(g + 8);
        if (type == 0) q2[n * H_NUM + h] = sq;
        if (type == 1) k2_t[h * N_TOK + n] = sq;
    }
}

// ---------- attention: lane = query; K/V tiles LDS-staged, double-buffered ----------
// grid (16, 12), 512 thr (8 waves). wave w computes j in [w*32, w*32+32) of each tile.
__global__ __launch_bounds__(512) void k_attn(
    const float* __restrict__ P, const float* __restrict__ qpg,
    const float* __restrict__ kpg_t, const float* __restrict__ vpg_t,
    const float* __restrict__ q2, const float* __restrict__ k2_t,
    const float* __restrict__ rot, const float* __restrict__ trans, float* __restrict__ att)
{
    __shared__ float smem[2 * BUF_F];   // 116.7 KB; reduction overlays it at the end
    int tid = threadIdx.x, lane = tid & 63, w = tid >> 6;
    int h = blockIdx.y;
    int i = blockIdx.x * 64 + lane;

    float q[16], qp[12];
    {
        const float4* qv = (const float4*)(P + i * PCOLS + Q0 + h * 16);
        *(float4*)(q + 0) = qv[0]; *(float4*)(q + 4) = qv[1];
        *(float4*)(q + 8) = qv[2]; *(float4*)(q + 12) = qv[3];
        const float4* qpv = (const float4*)(qpg + i * HP3_ROW + h * 12);
        *(float4*)(qp + 0) = qpv[0]; *(float4*)(qp + 4) = qpv[1]; *(float4*)(qp + 8) = qpv[2];
    }
    float qc = fmaf(-CC2, q2[i * H_NUM + h], -4.0f);

    const float* Pk    = P + K0 + h * 16;
    const float* Pv    = P + V0 + h * 16;
    const float* kpb_g = kpg_t + h * N_TOK * 12;
    const float* vpb_g = vpg_t + h * N_TOK * 12;
    const float* k2b_g = k2_t + h * N_TOK;

    float accv[16] = {}, accp[12] = {};
    float denom = 0.f;

    float4 rK[2], rV[2], rPP[3], rK2;

#define STAGE_LOAD(T) do {                                                   \
        int jt0 = (T) * TJ;                                                  \
        _Pragma("unroll")                                                    \
        for (int s = 0; s < 2; ++s) {                                        \
            int idx = tid + s * 512; int j = idx >> 2, f = idx & 3;          \
            rK[s] = *(const float4*)(Pk + (jt0 + j) * PCOLS + f * 4);        \
            rV[s] = *(const float4*)(Pv + (jt0 + j) * PCOLS + f * 4);        \
        }                                                                    \
        _Pragma("unroll")                                                    \
        for (int s = 0; s < 3; ++s) {                                        \
            int idx = tid + s * 512;                                         \
            int isVP = idx >= 768;                                           \
            int r = idx - (isVP ? 768 : 0);                                  \
            int j = r / 3, f = r % 3;                                        \
            const float* src = (isVP ? vpb_g : kpb_g) + (jt0 + j) * 12 + f * 4; \
            rPP[s] = *(const float4*)src;                                    \
        }                                                                    \
        if (tid < 64) rK2 = *(const float4*)(k2b_g + jt0 + tid * 4);         \
    } while (0)

#define STAGE_WRITE(T) do {                                                  \
        float* buf = smem + ((T) & 1) * BUF_F;                               \
        _Pragma("unroll")                                                    \
        for (int s = 0; s < 2; ++s) {                                        \
            int idx = tid + s * 512; int j = idx >> 2, f = idx & 3;          \
            *(float4*)(buf + OK_ + j * 16 + f * 4) = rK[s];                  \
            *(float4*)(buf + OV_ + j * 16 + f * 4) = rV[s];                  \
        }                                                                    \
        _Pragma("unroll")                                                    \
        for (int s = 0; s < 3; ++s) {                                        \
            int idx = tid + s * 512;                                         \
            int isVP = idx >= 768;                                           \
            int r = idx - (isVP ? 768 : 0);                                  \
            int j = r / 3, f = r % 3;                                        \
            *(float4*)(buf + (isVP ? OVP_ : OKP_) + j * 12 + f * 4) = rPP[s];\
        }                                                                    \
        if (tid < 64) *(float4*)(buf + OK2_ + tid * 4) = rK2;                \
    } while (0)

    STAGE_LOAD(0);
    STAGE_WRITE(0);
    __syncthreads();

    for (int t = 0; t < 4; ++t) {
        if (t < 3) STAGE_LOAD(t + 1);
        const float* buf = smem + (t & 1) * BUF_F;
        int jbase = w * 32;
#pragma unroll 2
        for (int jj = 0; jj < 32; ++jj) {
            int j = jbase + jj;
            float kk[16], kpv[12], vv[16], vpv[12];
            const float4* kb = (const float4*)(buf + OK_ + j * 16);
            *(float4*)(kk + 0) = kb[0]; *(float4*)(kk + 4) = kb[1];
            *(float4*)(kk + 8) = kb[2]; *(float4*)(kk + 12) = kb[3];
            const float4* kpb = (const float4*)(buf + OKP_ + j * 12);
            *(float4*)(kpv + 0) = kpb[0]; *(float4*)(kpv + 4) = kpb[1]; *(float4*)(kpv + 8) = kpb[2];
            float k2j = buf[OK2_ + j];

            float s = 0.f, pq = 0.f;
#pragma unroll
            for (int d = 0; d < 16; ++d) s = fmaf(q[d], kk[d], s);
#pragma unroll
            for (int c = 0; c < 12; ++c) pq = fmaf(qp[c], kpv[c], pq);
            float logit = fmaf(ISD, s, fmaf(2.f * CC2, pq, fmaf(-CC2, k2j, qc)));
            float p = __expf(logit);
            denom += p;

            const float4* vb = (const float4*)(buf + OV_ + j * 16);
            *(float4*)(vv + 0) = vb[0]; *(float4*)(vv + 4) = vb[1];
            *(float4*)(vv + 8) = vb[2]; *(float4*)(vv + 12) = vb[3];
            const float4* vpb = (const float4*)(buf + OVP_ + j * 12);
            *(float4*)(vpv + 0) = vpb[0]; *(float4*)(vpv + 4) = vpb[1]; *(float4*)(vpv + 8) = vpb[2];
#pragma unroll
            for (int d = 0; d < 16; ++d) accv[d] = fmaf(p, vv[d], accv[d]);
#pragma unroll
            for (int c = 0; c < 12; ++c) accp[c] = fmaf(p, vpv[c], accp[c]);
        }
        if (t < 3) STAGE_WRITE(t + 1);
        __syncthreads();
    }

    // reduction: red[w][c][lane] overlaid on smem
    float* red = smem;
#pragma unroll
    for (int d = 0; d < 16; ++d) red[(w * 29 + d) * 64 + lane] = accv[d];
#pragma unroll
    for (int c = 0; c < 12; ++c) red[(w * 29 + 16 + c) * 64 + lane] = accp[c];
    red[(w * 29 + 28) * 64 + lane] = denom;
    __syncthreads();

    for (int t2 = tid; t2 < 29 * 64; t2 += 512) {
        float s = red[t2];
#pragma unroll
        for (int ww = 1; ww < 8; ++ww) s += red[ww * 29 * 64 + t2];
        red[t2] = s;
    }
    __syncthreads();

    if (tid < 64) {
        float inv = 1.f / red[28 * 64 + lane];
        float* arow = att + i * ATT_W;
#pragma unroll
        for (int d = 0; d < 16; ++d) arow[h * 16 + d] = red[d * 64 + lane] * inv;
        float t0 = trans[i * 3 + 0], t1 = trans[i * 3 + 1], t2v = trans[i * 3 + 2];
        const float* R = rot + i * 9;
#pragma unroll
        for (int p = 0; p < 4; ++p) {
            float c0 = red[(16 + p * 3 + 0) * 64 + lane] * inv - t0;
            float c1 = red[(16 + p * 3 + 1) * 64 + lane] * inv - t1;
            float c2 = red[(16 + p * 3 + 2) * 64 + lane] * inv - t2v;
            float l0 = R[0] * c0 + R[3] * c1 + R[6] * c2;
            float l1 = R[1] * c0 + R[4] * c1 + R[7] * c2;
            float l2 = R[2] * c0 + R[5] * c1 + R[8] * c2;
            arow[192 + h * 4 + p] = sqrtf(l0 * l0 + l1 * l1 + l2 * l2);
        }
    }
}

// ---------- out GEMM: out[1024][384] = att[1024][240] @ Wout[240][384] + bout ----------
__global__ __launch_bounds__(256) void k_out(
    const float* __restrict__ att, const float* __restrict__ Wout,
    const float* __restrict__ bout, float* __restrict__ out)
{
    __shared__ float xs[64][17];
    __shared__ float wsh[16][64];
    int tid = threadIdx.x;
    int i0 = blockIdx.x * 64, c0 = blockIdx.y * 64;
    int lr = tid >> 2, lk = (tid & 3) * 4;
    int wr = tid >> 4, wc = (tid & 15) * 4;
    int ty = tid >> 4, tx = tid & 15;

    float4 xa = *(const float4*)(att + (i0 + lr) * ATT_W + lk);
    float4 wa = *(const float4*)(Wout + wr * C_DIM + c0 + wc);
    float acc[4][4] = {};

    for (int it = 0; it < 15; ++it) {
        xs[lr][lk + 0] = xa.x; xs[lr][lk + 1] = xa.y;
        xs[lr][lk + 2] = xa.z; xs[lr][lk + 3] = xa.w;
        *(float4*)&wsh[wr][wc] = wa;
        __syncthreads();
        if (it < 14) {
            xa = *(const float4*)(att + (i0 + lr) * ATT_W + (it + 1) * 16 + lk);
            wa = *(const float4*)(Wout + ((it + 1) * 16 + wr) * C_DIM + c0 + wc);
        }
#pragma unroll
        for (int kk = 0; kk < 16; ++kk) {
            float4 b = *(float4*)&wsh[kk][tx * 4];
            float a0 = xs[ty * 4 + 0][kk];
            float a1 = xs[ty * 4 + 1][kk];
            float a2 = xs[ty * 4 + 2][kk];
            float a3 = xs[ty * 4 + 3][kk];
            acc[0][0] = fmaf(a0, b.x, acc[0][0]); acc[0][1] = fmaf(a0, b.y, acc[0][1]);
            acc[0][2] = fmaf(a0, b.z, acc[0][2]); acc[0][3] = fmaf(a0, b.w, acc[0][3]);
            acc[1][0] = fmaf(a1, b.x, acc[1][0]); acc[1][1] = fmaf(a1, b.y, acc[1][1]);
            acc[1][2] = fmaf(a1, b.z, acc[1][2]); acc[1][3] = fmaf(a1, b.w, acc[1][3]);
            acc[2][0] = fmaf(a2, b.x, acc[2][0]); acc[2][1] = fmaf(a2, b.y, acc[2][1]);
            acc[2][2] = fmaf(a2, b.z, acc[2][2]); acc[2][3] = fmaf(a2, b.w, acc[2][3]);
            acc[3][0] = fmaf(a3, b.x, acc[3][0]); acc[3][1] = fmaf(a3, b.y, acc[3][1]);
            acc[3][2] = fmaf(a3, b.z, acc[3][2]); acc[3][3] = fmaf(a3, b.w, acc[3][3]);
        }
        __syncthreads();
    }
    float4 bb = *(const float4*)(bout + c0 + tx * 4);
#pragma unroll
    for (int r = 0; r < 4; ++r) {
        *(float4*)(out + (i0 + ty * 4 + r) * C_DIM + c0 + tx * 4) =
            make_float4(acc[r][0] + bb.x, acc[r][1] + bb.y, acc[r][2] + bb.z, acc[r][3] + bb.w);
    }
}

extern "C" void kernel_launch(void* const* d_in, const int* in_sizes, int n_in,
                              void* d_out, int out_size, void* d_ws, size_t ws_size,
                              hipStream_t stream) {
    const float* x     = (const float*)d_in[0];
    const float* rot   = (const float*)d_in[1];
    const float* trans = (const float*)d_in[2];
    const float* Wq    = (const float*)d_in[3];
    const float* Wk    = (const float*)d_in[4];
    const float* Wv    = (const float*)d_in[5];
    const float* Wqp   = (const float*)d_in[6];
    const float* Wkp   = (const float*)d_in[7];
    const float* Wvp   = (const float*)d_in[8];
    const float* Wout  = (const float*)d_in[9];
    const float* bout  = (const float*)d_in[10];
    float* out = (float*)d_out;

    float* ws = (float*)d_ws;
    float* Wall  = ws;                          // 384*1024
    float* P     = Wall  + C_DIM * PCOLS;       // 1024*1024
    float* qpg   = P     + N_TOK * PCOLS;       // 1024*144 (natural)
    float* kpg_t = qpg   + N_TOK * HP3_ROW;     // [h][j][12]
    float* vpg_t = kpg_t + N_TOK * HP3_ROW;     // [h][j][12]
    float* q2    = vpg_t + N_TOK * HP3_ROW;     // [n][h]
    float* k2_t  = q2    + N_TOK * H_NUM;       // [h][j]
    float* att   = k2_t  + N_TOK * H_NUM;       // 1024*240

    k_pack<<<384, 256, 0, stream>>>(Wq, Wk, Wv, Wqp, Wkp, Wvp, Wall);
    k_proj<<<dim3(16, 16), 256, 0, stream>>>(x, Wall, P);
    k_rotsq<<<(N_TOK * H_NUM + 255) / 256, 256, 0, stream>>>(P, rot, trans,
                                                             qpg, kpg_t, vpg_t, q2, k2_t);
    k_attn<<<dim3(16, 12), 512, 0, stream>>>(P, qpg, kpg_t, vpg_t, q2, k2_t,
                                             rot, trans, att);
    k_out<<<dim3(16, 6), 256, 0, stream>>>(att, Wout, bout, out);
}

// Round 6
// 97.028 us; speedup vs baseline: 8.0295x; 1.0772x over previous
//
#include <hip/hip_runtime.h>
#include <math.h>

#define N_TOK 1024
#define C_DIM 384
#define H_NUM 12
#define PCOLS 1024
#define HP3_ROW 144
#define Q0 0
#define K0 192
#define V0 384
#define QP0 576
#define KP0 720
#define VP0 864
#define ATT_W 240
#define COEF 0.11785113019775792f   // 0.5*sqrt(2/36)
#define ISD 0.25f
#define CC2 (COEF * ISD)            // 0.029462...

// LDS tile layout (floats), tile = 128 keys
#define TJ 128
#define OK_ 0
#define OV_ 2048
#define OKP_ 4096
#define OVP_ 5632
#define OK2_ 7168
#define BUF_F 7296
#define SMEM_F 14848   // max(2*BUF_F=14592, reduction 8*29*64=14848)

// ---------- pack 6 weight mats into Wall[384][1024] (cols 1008..1023 zero) ----------
__global__ __launch_bounds__(256) void k_pack(
    const float* __restrict__ Wq, const float* __restrict__ Wk, const float* __restrict__ Wv,
    const float* __restrict__ Wqp, const float* __restrict__ Wkp, const float* __restrict__ Wvp,
    float* __restrict__ Wall)
{
    int t = blockIdx.x * 256 + threadIdx.x;      // 384*256 threads
    int k = t >> 8;
    int col = (t & 255) * 4;
    float4 v;
    if (col < 192)       v = *(const float4*)(Wq  + k * 192 + col);
    else if (col < 384)  v = *(const float4*)(Wk  + k * 192 + col - 192);
    else if (col < 576)  v = *(const float4*)(Wv  + k * 192 + col - 384);
    else if (col < 720)  v = *(const float4*)(Wqp + k * 144 + col - 576);
    else if (col < 864)  v = *(const float4*)(Wkp + k * 144 + col - 720);
    else if (col < 1008) v = *(const float4*)(Wvp + k * 144 + col - 864);
    else                 v = make_float4(0.f, 0.f, 0.f, 0.f);
    *(float4*)(Wall + k * PCOLS + col) = v;
}

// ---------- proj GEMM: P[1024][1024] = x[1024][384] @ Wall[384][1024] ----------
__global__ __launch_bounds__(256) void k_proj(
    const float* __restrict__ x, const float* __restrict__ Wall, float* __restrict__ P)
{
    __shared__ float xs[64][17];
    __shared__ float wsh[16][64];
    int tid = threadIdx.x;
    int i0 = blockIdx.x * 64, c0 = blockIdx.y * 64;
    int lr = tid >> 2, lk = (tid & 3) * 4;
    int wr = tid >> 4, wc = (tid & 15) * 4;
    int ty = tid >> 4, tx = tid & 15;

    float4 xa = *(const float4*)(x + (i0 + lr) * C_DIM + lk);
    float4 wa = *(const float4*)(Wall + wr * PCOLS + c0 + wc);
    float acc[4][4] = {};

    for (int it = 0; it < 24; ++it) {
        xs[lr][lk + 0] = xa.x; xs[lr][lk + 1] = xa.y;
        xs[lr][lk + 2] = xa.z; xs[lr][lk + 3] = xa.w;
        *(float4*)&wsh[wr][wc] = wa;
        __syncthreads();
        if (it < 23) {
            xa = *(const float4*)(x + (i0 + lr) * C_DIM + (it + 1) * 16 + lk);
            wa = *(const float4*)(Wall + ((it + 1) * 16 + wr) * PCOLS + c0 + wc);
        }
#pragma unroll
        for (int kk = 0; kk < 16; ++kk) {
            float4 b = *(float4*)&wsh[kk][tx * 4];
            float a0 = xs[ty * 4 + 0][kk];
            float a1 = xs[ty * 4 + 1][kk];
            float a2 = xs[ty * 4 + 2][kk];
            float a3 = xs[ty * 4 + 3][kk];
            acc[0][0] = fmaf(a0, b.x, acc[0][0]); acc[0][1] = fmaf(a0, b.y, acc[0][1]);
            acc[0][2] = fmaf(a0, b.z, acc[0][2]); acc[0][3] = fmaf(a0, b.w, acc[0][3]);
            acc[1][0] = fmaf(a1, b.x, acc[1][0]); acc[1][1] = fmaf(a1, b.y, acc[1][1]);
            acc[1][2] = fmaf(a1, b.z, acc[1][2]); acc[1][3] = fmaf(a1, b.w, acc[1][3]);
            acc[2][0] = fmaf(a2, b.x, acc[2][0]); acc[2][1] = fmaf(a2, b.y, acc[2][1]);
            acc[2][2] = fmaf(a2, b.z, acc[2][2]); acc[2][3] = fmaf(a2, b.w, acc[2][3]);
            acc[3][0] = fmaf(a3, b.x, acc[3][0]); acc[3][1] = fmaf(a3, b.y, acc[3][1]);
            acc[3][2] = fmaf(a3, b.z, acc[3][2]); acc[3][3] = fmaf(a3, b.w, acc[3][3]);
        }
        __syncthreads();
    }
#pragma unroll
    for (int r = 0; r < 4; ++r) {
        *(float4*)(P + (i0 + ty * 4 + r) * PCOLS + c0 + tx * 4) =
            make_float4(acc[r][0], acc[r][1], acc[r][2], acc[r][3]);
    }
}

// ---------- rot/translate/sq-norm; kp/vp/k2 written head-transposed ----------
__global__ __launch_bounds__(256) void k_rotsq(
    const float* __restrict__ P, const float* __restrict__ rot, const float* __restrict__ trans,
    float* __restrict__ qpg, float* __restrict__ kpg_t, float* __restrict__ vpg_t,
    float* __restrict__ q2, float* __restrict__ k2_t)
{
    int t = blockIdx.x * 256 + threadIdx.x;
    if (t >= N_TOK * H_NUM) return;
    int n = t / H_NUM, h = t % H_NUM;
    const float* R = rot + n * 9;
    float R00 = R[0], R01 = R[1], R02 = R[2];
    float R10 = R[3], R11 = R[4], R12 = R[5];
    float R20 = R[6], R21 = R[7], R22 = R[8];
    float t0 = trans[n * 3 + 0], t1 = trans[n * 3 + 1], t2 = trans[n * 3 + 2];

#pragma unroll
    for (int type = 0; type < 3; ++type) {
        int srcoff = (type == 0) ? QP0 : (type == 1) ? KP0 : VP0;
        const float* src = P + n * PCOLS + srcoff + h * 12;
        float p[12];
        *(float4*)(p + 0) = ((const float4*)src)[0];
        *(float4*)(p + 4) = ((const float4*)src)[1];
        *(float4*)(p + 8) = ((const float4*)src)[2];
        float g[12];
        float sq = 0.f;
#pragma unroll
        for (int pt = 0; pt < 4; ++pt) {
            float p0 = p[pt * 3 + 0], p1 = p[pt * 3 + 1], p2 = p[pt * 3 + 2];
            float g0 = R00 * p0 + R01 * p1 + R02 * p2 + t0;
            float g1 = R10 * p0 + R11 * p1 + R12 * p2 + t1;
            float g2 = R20 * p0 + R21 * p1 + R22 * p2 + t2;
            g[pt * 3 + 0] = g0; g[pt * 3 + 1] = g1; g[pt * 3 + 2] = g2;
            sq += g0 * g0 + g1 * g1 + g2 * g2;
        }
        float* dst;
        if (type == 0)      dst = qpg + n * HP3_ROW + h * 12;
        else if (type == 1) dst = kpg_t + (h * N_TOK + n) * 12;
        else                dst = vpg_t + (h * N_TOK + n) * 12;
        ((float4*)dst)[0] = *(float4*)(g + 0);
        ((float4*)dst)[1] = *(float4*)(g + 4);
        ((float4*)dst)[2] = *(float4*)(g + 8);
        if (type == 0) q2[n * H_NUM + h] = sq;
        if (type == 1) k2_t[h * N_TOK + n] = sq;
    }
}

// ---------- attention partials: lane = query, z-split over keys ----------
// grid (16, 12, 2), 512 thr (8 waves). Block z covers j in [z*512, z*512+512), 4 tiles of 128.
// Writes un-normalized partials part[((z*12+h)*29 + c)*1024 + i].
__global__ __launch_bounds__(512) void k_attn(
    const float* __restrict__ P, const float* __restrict__ qpg,
    const float* __restrict__ kpg_t, const float* __restrict__ vpg_t,
    const float* __restrict__ q2, const float* __restrict__ k2_t,
    float* __restrict__ part)
{
    __shared__ float smem[SMEM_F];   // 59392 B -> 2 blocks/CU
    int tid = threadIdx.x, lane = tid & 63, w = tid >> 6;
    int h = blockIdx.y;
    int i = blockIdx.x * 64 + lane;
    int jz0 = blockIdx.z * 512;

    float q[16], qp[12];
    {
        const float4* qv = (const float4*)(P + i * PCOLS + Q0 + h * 16);
        *(float4*)(q + 0) = qv[0]; *(float4*)(q + 4) = qv[1];
        *(float4*)(q + 8) = qv[2]; *(float4*)(q + 12) = qv[3];
        const float4* qpv = (const float4*)(qpg + i * HP3_ROW + h * 12);
        *(float4*)(qp + 0) = qpv[0]; *(float4*)(qp + 4) = qpv[1]; *(float4*)(qp + 8) = qpv[2];
    }
    float qc = fmaf(-CC2, q2[i * H_NUM + h], -4.0f);

    const float* Pk    = P + K0 + h * 16;
    const float* Pv    = P + V0 + h * 16;
    const float* kpb_g = kpg_t + h * N_TOK * 12;
    const float* vpb_g = vpg_t + h * N_TOK * 12;
    const float* k2b_g = k2_t + h * N_TOK;

    float accv[16] = {}, accp[12] = {};
    float denom = 0.f;

    float4 rK, rV, rPP0, rPP1, rK2;

#define STAGE_LOAD(T) do {                                                     \
        int jt0 = jz0 + (T) * TJ;                                              \
        { int j = tid >> 2, f = tid & 3;                                       \
          rK = *(const float4*)(Pk + (jt0 + j) * PCOLS + f * 4);               \
          rV = *(const float4*)(Pv + (jt0 + j) * PCOLS + f * 4); }             \
        { int isVP = tid >= 384; int r = tid - (isVP ? 384 : 0);               \
          int j = r / 3, f = r % 3;                                            \
          rPP0 = *(const float4*)((isVP ? vpb_g : kpb_g) + (jt0 + j) * 12 + f * 4); } \
        if (tid < 256) { int r = tid + 128;                                    \
          int j = r / 3, f = r % 3;                                            \
          rPP1 = *(const float4*)(vpb_g + (jt0 + j) * 12 + f * 4); }           \
        if (tid < 32) rK2 = *(const float4*)(k2b_g + jt0 + tid * 4);           \
    } while (0)

#define STAGE_WRITE(T) do {                                                    \
        float* buf = smem + ((T) & 1) * BUF_F;                                 \
        { int j = tid >> 2, f = tid & 3;                                       \
          *(float4*)(buf + OK_ + j * 16 + f * 4) = rK;                         \
          *(float4*)(buf + OV_ + j * 16 + f * 4) = rV; }                       \
        { int isVP = tid >= 384; int r = tid - (isVP ? 384 : 0);               \
          int j = r / 3, f = r % 3;                                            \
          *(float4*)(buf + (isVP ? OVP_ : OKP_) + j * 12 + f * 4) = rPP0; }    \
        if (tid < 256) { int r = tid + 128;                                    \
          int j = r / 3, f = r % 3;                                            \
          *(float4*)(buf + OVP_ + j * 12 + f * 4) = rPP1; }                    \
        if (tid < 32) *(float4*)(buf + OK2_ + tid * 4) = rK2;                  \
    } while (0)

    STAGE_LOAD(0);
    STAGE_WRITE(0);
    __syncthreads();

    for (int t = 0; t < 4; ++t) {
        if (t < 3) STAGE_LOAD(t + 1);
        const float* buf = smem + (t & 1) * BUF_F;
        int jbase = w * 16;
#pragma unroll 2
        for (int jj = 0; jj < 16; ++jj) {
            int j = jbase + jj;
            float kk[16], kpv[12], vv[16], vpv[12];
            const float4* kb = (const float4*)(buf + OK_ + j * 16);
            *(float4*)(kk + 0) = kb[0]; *(float4*)(kk + 4) = kb[1];
            *(float4*)(kk + 8) = kb[2]; *(float4*)(kk + 12) = kb[3];
            const float4* kpb = (const float4*)(buf + OKP_ + j * 12);
            *(float4*)(kpv + 0) = kpb[0]; *(float4*)(kpv + 4) = kpb[1]; *(float4*)(kpv + 8) = kpb[2];
            float k2j = buf[OK2_ + j];

            float s = 0.f, pq = 0.f;
#pragma unroll
            for (int d = 0; d < 16; ++d) s = fmaf(q[d], kk[d], s);
#pragma unroll
            for (int c = 0; c < 12; ++c) pq = fmaf(qp[c], kpv[c], pq);
            float logit = fmaf(ISD, s, fmaf(2.f * CC2, pq, fmaf(-CC2, k2j, qc)));
            float p = __expf(logit);
            denom += p;

            const float4* vb = (const float4*)(buf + OV_ + j * 16);
            *(float4*)(vv + 0) = vb[0]; *(float4*)(vv + 4) = vb[1];
            *(float4*)(vv + 8) = vb[2]; *(float4*)(vv + 12) = vb[3];
            const float4* vpb = (const float4*)(buf + OVP_ + j * 12);
            *(float4*)(vpv + 0) = vpb[0]; *(float4*)(vpv + 4) = vpb[1]; *(float4*)(vpv + 8) = vpb[2];
#pragma unroll
            for (int d = 0; d < 16; ++d) accv[d] = fmaf(p, vv[d], accv[d]);
#pragma unroll
            for (int c = 0; c < 12; ++c) accp[c] = fmaf(p, vpv[c], accp[c]);
        }
        if (t < 3) STAGE_WRITE(t + 1);
        __syncthreads();
    }

    // cross-wave reduction overlaid on smem: red[w][c][lane]
    float* red = smem;
#pragma unroll
    for (int d = 0; d < 16; ++d) red[(w * 29 + d) * 64 + lane] = accv[d];
#pragma unroll
    for (int c = 0; c < 12; ++c) red[(w * 29 + 16 + c) * 64 + lane] = accp[c];
    red[(w * 29 + 28) * 64 + lane] = denom;
    __syncthreads();

    for (int t2 = tid; t2 < 29 * 64; t2 += 512) {
        float s = red[t2];
#pragma unroll
        for (int ww = 1; ww < 8; ++ww) s += red[ww * 29 * 64 + t2];
        part[((blockIdx.z * H_NUM + h) * 29 + (t2 >> 6)) * N_TOK + blockIdx.x * 64 + (t2 & 63)] = s;
    }
}

// ---------- combine partials, normalize, point-norm epilogue ----------
// grid 48, block 256. thread t = h*1024 + i.
__global__ __launch_bounds__(256) void k_comb(
    const float* __restrict__ part, const float* __restrict__ rot,
    const float* __restrict__ trans, float* __restrict__ att)
{
    int t = blockIdx.x * 256 + threadIdx.x;
    int h = t >> 10, i = t & 1023;
    float v[29];
#pragma unroll
    for (int c = 0; c < 29; ++c) {
        v[c] = part[(h * 29 + c) * N_TOK + i] +
               part[((H_NUM + h) * 29 + c) * N_TOK + i];
    }
    float inv = 1.f / v[28];
    float* arow = att + i * ATT_W;
#pragma unroll
    for (int d = 0; d < 16; ++d) arow[h * 16 + d] = v[d] * inv;
    float t0 = trans[i * 3 + 0], t1 = trans[i * 3 + 1], t2v = trans[i * 3 + 2];
    const float* R = rot + i * 9;
#pragma unroll
    for (int p = 0; p < 4; ++p) {
        float c0 = v[16 + p * 3 + 0] * inv - t0;
        float c1 = v[16 + p * 3 + 1] * inv - t1;
        float c2 = v[16 + p * 3 + 2] * inv - t2v;
        float l0 = R[0] * c0 + R[3] * c1 + R[6] * c2;
        float l1 = R[1] * c0 + R[4] * c1 + R[7] * c2;
        float l2 = R[2] * c0 + R[5] * c1 + R[8] * c2;
        arow[192 + h * 4 + p] = sqrtf(l0 * l0 + l1 * l1 + l2 * l2);
    }
}

// ---------- out GEMM: out[1024][384] = att[1024][240] @ Wout[240][384] + bout ----------
__global__ __launch_bounds__(256) void k_out(
    const float* __restrict__ att, const float* __restrict__ Wout,
    const float* __restrict__ bout, float* __restrict__ out)
{
    __shared__ float xs[64][17];
    __shared__ float wsh[16][64];
    int tid = threadIdx.x;
    int i0 = blockIdx.x * 64, c0 = blockIdx.y * 64;
    int lr = tid >> 2, lk = (tid & 3) * 4;
    int wr = tid >> 4, wc = (tid & 15) * 4;
    int ty = tid >> 4, tx = tid & 15;

    float4 xa = *(const float4*)(att + (i0 + lr) * ATT_W + lk);
    float4 wa = *(const float4*)(Wout + wr * C_DIM + c0 + wc);
    float acc[4][4] = {};

    for (int it = 0; it < 15; ++it) {
        xs[lr][lk + 0] = xa.x; xs[lr][lk + 1] = xa.y;
        xs[lr][lk + 2] = xa.z; xs[lr][lk + 3] = xa.w;
        *(float4*)&wsh[wr][wc] = wa;
        __syncthreads();
        if (it < 14) {
            xa = *(const float4*)(att + (i0 + lr) * ATT_W + (it + 1) * 16 + lk);
            wa = *(const float4*)(Wout + ((it + 1) * 16 + wr) * C_DIM + c0 + wc);
        }
#pragma unroll
        for (int kk = 0; kk < 16; ++kk) {
            float4 b = *(float4*)&wsh[kk][tx * 4];
            float a0 = xs[ty * 4 + 0][kk];
            float a1 = xs[ty * 4 + 1][kk];
            float a2 = xs[ty * 4 + 2][kk];
            float a3 = xs[ty * 4 + 3][kk];
            acc[0][0] = fmaf(a0, b.x, acc[0][0]); acc[0][1] = fmaf(a0, b.y, acc[0][1]);
            acc[0][2] = fmaf(a0, b.z, acc[0][2]); acc[0][3] = fmaf(a0, b.w, acc[0][3]);
            acc[1][0] = fmaf(a1, b.x, acc[1][0]); acc[1][1] = fmaf(a1, b.y, acc[1][1]);
            acc[1][2] = fmaf(a1, b.z, acc[1][2]); acc[1][3] = fmaf(a1, b.w, acc[1][3]);
            acc[2][0] = fmaf(a2, b.x, acc[2][0]); acc[2][1] = fmaf(a2, b.y, acc[2][1]);
            acc[2][2] = fmaf(a2, b.z, acc[2][2]); acc[2][3] = fmaf(a2, b.w, acc[2][3]);
            acc[3][0] = fmaf(a3, b.x, acc[3][0]); acc[3][1] = fmaf(a3, b.y, acc[3][1]);
            acc[3][2] = fmaf(a3, b.z, acc[3][2]); acc[3][3] = fmaf(a3, b.w, acc[3][3]);
        }
        __syncthreads();
    }
    float4 bb = *(const float4*)(bout + c0 + tx * 4);
#pragma unroll
    for (int r = 0; r < 4; ++r) {
        *(float4*)(out + (i0 + ty * 4 + r) * C_DIM + c0 + tx * 4) =
            make_float4(acc[r][0] + bb.x, acc[r][1] + bb.y, acc[r][2] + bb.z, acc[r][3] + bb.w);
    }
}

extern "C" void kernel_launch(void* const* d_in, const int* in_sizes, int n_in,
                              void* d_out, int out_size, void* d_ws, size_t ws_size,
                              hipStream_t stream) {
    const float* x     = (const float*)d_in[0];
    const float* rot   = (const float*)d_in[1];
    const float* trans = (const float*)d_in[2];
    const float* Wq    = (const float*)d_in[3];
    const float* Wk    = (const float*)d_in[4];
    const float* Wv    = (const float*)d_in[5];
    const float* Wqp   = (const float*)d_in[6];
    const float* Wkp   = (const float*)d_in[7];
    const float* Wvp   = (const float*)d_in[8];
    const float* Wout  = (const float*)d_in[9];
    const float* bout  = (const float*)d_in[10];
    float* out = (float*)d_out;

    float* ws = (float*)d_ws;
    float* Wall  = ws;                          // 384*1024
    float* P     = Wall  + C_DIM * PCOLS;       // 1024*1024
    float* qpg   = P     + N_TOK * PCOLS;       // 1024*144 (natural)
    float* kpg_t = qpg   + N_TOK * HP3_ROW;     // [h][j][12]
    float* vpg_t = kpg_t + N_TOK * HP3_ROW;     // [h][j][12]
    float* q2    = vpg_t + N_TOK * HP3_ROW;     // [n][h]
    float* k2_t  = q2    + N_TOK * H_NUM;       // [h][j]
    float* att   = k2_t  + N_TOK * H_NUM;       // 1024*240
    float* part  = att   + N_TOK * ATT_W;       // 2*12*29*1024

    k_pack<<<384, 256, 0, stream>>>(Wq, Wk, Wv, Wqp, Wkp, Wvp, Wall);
    k_proj<<<dim3(16, 16), 256, 0, stream>>>(x, Wall, P);
    k_rotsq<<<(N_TOK * H_NUM + 255) / 256, 256, 0, stream>>>(P, rot, trans,
                                                             qpg, kpg_t, vpg_t, q2, k2_t);
    k_attn<<<dim3(16, 12, 2), 512, 0, stream>>>(P, qpg, kpg_t, vpg_t, q2, k2_t, part);
    k_comb<<<48, 256, 0, stream>>>(part, rot, trans, att);
    k_out<<<dim3(16, 6), 256, 0, stream>>>(att, Wout, bout, out);
}